// Round 2
// baseline (412.447 us; speedup 1.0000x reference)
//
#include <hip/hip_runtime.h>
#include <hip/hip_bf16.h>
#include <stdint.h>

// Problem: B=4, N=2048, C=1024, H=16, D=64.
// Device dtypes: ALL inputs fp32, output fp32 (per reference). Internal compute:
// bf16 MFMA with fp32 accumulate; intermediates in d_ws as bf16.
// x[B,N,C] @ Wqkv.T -> qkv -> RoPE(q,k) -> per-(b,h) softmax(q k^T /8 + mask) v
// -> [B,N,C] @ Wproj.T + bproj -> out[B,N,C]

typedef __bf16 bf16;
typedef __bf16 bf16x4 __attribute__((ext_vector_type(4)));
typedef __bf16 bf16x8 __attribute__((ext_vector_type(8)));
typedef float  f32x4  __attribute__((ext_vector_type(4)));
typedef int    int4v  __attribute__((ext_vector_type(4)));

#define MFMA16(a, b, c) __builtin_amdgcn_mfma_f32_16x16x32_bf16((a), (b), (c), 0, 0, 0)

__device__ __forceinline__ bf16x4 cvt4(f32x4 v) {
  bf16x4 r;
  r[0] = (bf16)v[0]; r[1] = (bf16)v[1]; r[2] = (bf16)v[2]; r[3] = (bf16)v[3];
  return r;
}

// ---------------------------------------------------------------------------
// GEMM: C[m][n] = sum_k A[m][k] * B[n][k]   (both K-contiguous, bf16 MFMA)
// MODE 0: A = x (fp32, 8192x1024), B = Wqkv (fp32, 3072x1024).
//         Epilogue scatters: Q,K -> [BH][N][64] bf16 ; V -> VT [BH][64][N] bf16.
// MODE 1: A = Ob (bf16, 8192x1024), B = Wproj (fp32, 1024x1024), + bias.
//         Epilogue -> out fp32 row-major [8192][1024].
// ---------------------------------------------------------------------------
template<int MODE>
__global__ __launch_bounds__(256)
void gemm_bt(const void* __restrict__ Av, const float* __restrict__ B,
             void* __restrict__ O0, bf16* __restrict__ O1, bf16* __restrict__ O2,
             const float* __restrict__ bias)
{
  constexpr int K = 1024;
  __shared__ __attribute__((aligned(16))) bf16 As[128 * 64];
  __shared__ __attribute__((aligned(16))) bf16 Bs[128 * 64];
  const int tid = threadIdx.x, lane = tid & 63, wid = tid >> 6;
  const int m0 = blockIdx.x * 128, n0 = blockIdx.y * 128;
  const int wm = (wid >> 1) * 64, wn = (wid & 1) * 64;
  const int l15 = lane & 15, lg = lane >> 4;

  f32x4 acc[4][4] = {};

  for (int k0 = 0; k0 < K; k0 += 64) {
    // stage B tile (128x64 fp32 -> bf16): 8 x f32x4 per thread, coalesced
#pragma unroll
    for (int it = 0; it < 8; ++it) {
      const int e = (it * 256 + tid) * 4;   // elem index in 128x64 tile
      const int row = e >> 6, col = e & 63;
      *(bf16x4*)(Bs + row * 64 + col) =
          cvt4(*(const f32x4*)(B + (size_t)(n0 + row) * K + k0 + col));
    }
    if (MODE == 0) {
      const float* A = (const float*)Av;
#pragma unroll
      for (int it = 0; it < 8; ++it) {
        const int e = (it * 256 + tid) * 4;
        const int row = e >> 6, col = e & 63;
        *(bf16x4*)(As + row * 64 + col) =
            cvt4(*(const f32x4*)(A + (size_t)(m0 + row) * K + k0 + col));
      }
    } else {
      const bf16* A = (const bf16*)Av;
#pragma unroll
      for (int it = 0; it < 4; ++it) {
        const int e = (it * 256 + tid) * 8;
        const int row = e >> 6, col = e & 63;
        *(bf16x8*)(As + row * 64 + col) =
            *(const bf16x8*)(A + (size_t)(m0 + row) * K + k0 + col);
      }
    }
    __syncthreads();

    bf16x8 af[4][2], bb[4][2];
#pragma unroll
    for (int i = 0; i < 4; ++i)
#pragma unroll
      for (int kk = 0; kk < 2; ++kk) {
        af[i][kk] = *(const bf16x8*)(As + (wm + i * 16 + l15) * 64 + kk * 32 + lg * 8);
        bb[i][kk] = *(const bf16x8*)(Bs + (wn + i * 16 + l15) * 64 + kk * 32 + lg * 8);
      }
#pragma unroll
    for (int mi = 0; mi < 4; ++mi)
#pragma unroll
      for (int ni = 0; ni < 4; ++ni)
#pragma unroll
        for (int kk = 0; kk < 2; ++kk)
          acc[mi][ni] = MFMA16(af[mi][kk], bb[ni][kk], acc[mi][ni]);
    __syncthreads();
  }

  // epilogue. C/D layout (m89/m91): col = lane&15, row = 4*(lane>>4)+r
#pragma unroll
  for (int mi = 0; mi < 4; ++mi)
#pragma unroll
    for (int ni = 0; ni < 4; ++ni)
#pragma unroll
      for (int r = 0; r < 4; ++r) {
        const int row = m0 + wm + mi * 16 + lg * 4 + r;
        const int col = n0 + wn + ni * 16 + l15;
        float v = acc[mi][ni][r];
        if (MODE == 0) {
          const int s = col >> 10, h = (col >> 6) & 15, d = col & 63;
          const int b = row >> 11, n = row & 2047;
          const bf16 bv = (bf16)v;
          if (s == 0)
            ((bf16*)O0)[(((size_t)(b * 16 + h) * 2048) + n) * 64 + d] = bv;
          else if (s == 1)
            O1[(((size_t)(b * 16 + h) * 2048) + n) * 64 + d] = bv;
          else  // V, stored transposed: VT[bh][d][n]
            O2[(((size_t)(b * 16 + h) * 64) + d) * 2048 + n] = bv;
        } else {
          ((float*)O0)[(size_t)row * 1024 + col] = v + bias[col];
        }
      }
}

// ---------------------------------------------------------------------------
// RoPE in place on Q and K ([BH][N][64] bf16). cos/sin are fp32 [B][N][32].
// ---------------------------------------------------------------------------
__global__ __launch_bounds__(256)
void rope_k(bf16* __restrict__ Q, bf16* __restrict__ K,
            const float* __restrict__ C, const float* __restrict__ S)
{
  const int gid = blockIdx.x * 256 + threadIdx.x;  // [0, 64*2048*4)
  const int part = gid & 3;                         // 16-elem quarter of a row
  const int rowid = gid >> 2;                       // bh*2048 + n
  const int n = rowid & 2047;
  const int b = rowid >> 15;
  const size_t cbase = ((size_t)(b * 2048 + n)) * 32 + part * 8;

  float cf[8], sf[8];
  *(f32x4*)cf = *(const f32x4*)(C + cbase);
  *(f32x4*)(cf + 4) = *(const f32x4*)(C + cbase + 4);
  *(f32x4*)sf = *(const f32x4*)(S + cbase);
  *(f32x4*)(sf + 4) = *(const f32x4*)(S + cbase + 4);

  bf16* qp = Q + (size_t)rowid * 64 + part * 16;
  bf16* kp = K + (size_t)rowid * 64 + part * 16;
  __attribute__((aligned(16))) bf16 buf[16];

  *(int4v*)buf = *(const int4v*)qp;
  *(int4v*)(buf + 8) = *(const int4v*)(qp + 8);
#pragma unroll
  for (int j = 0; j < 8; ++j) {
    const float t0 = (float)buf[2 * j], t1 = (float)buf[2 * j + 1];
    buf[2 * j]     = (bf16)(t0 * cf[j] - t1 * sf[j]);
    buf[2 * j + 1] = (bf16)(t0 * sf[j] + t1 * cf[j]);
  }
  *(int4v*)qp = *(int4v*)buf;
  *(int4v*)(qp + 8) = *(int4v*)(buf + 8);

  *(int4v*)buf = *(const int4v*)kp;
  *(int4v*)(buf + 8) = *(const int4v*)(kp + 8);
#pragma unroll
  for (int j = 0; j < 8; ++j) {
    const float t0 = (float)buf[2 * j], t1 = (float)buf[2 * j + 1];
    buf[2 * j]     = (bf16)(t0 * cf[j] - t1 * sf[j]);
    buf[2 * j + 1] = (bf16)(t0 * sf[j] + t1 * cf[j]);
  }
  *(int4v*)kp = *(int4v*)buf;
  *(int4v*)(kp + 8) = *(int4v*)(buf + 8);
}

// ---------------------------------------------------------------------------
// Flash attention: 4 waves x 16 q-rows per block, KVBLK=64, online softmax.
// Q,K: [BH][2048][64] bf16; VT: [BH][64][2048] bf16; mask fp32 [2048][2048];
// O: [8192][1024] bf16.
// ---------------------------------------------------------------------------
__global__ __launch_bounds__(256)
void attn_k(const bf16* __restrict__ Q, const bf16* __restrict__ K,
            const bf16* __restrict__ VT, const float* __restrict__ M,
            bf16* __restrict__ O)
{
  constexpr float SCALE = 0.125f;
  __shared__ __attribute__((aligned(16))) bf16 Kt[64 * 72];
  __shared__ __attribute__((aligned(16))) bf16 Vt[64 * 72];
  __shared__ __attribute__((aligned(16))) bf16 Mt[64 * 72];
  __shared__ __attribute__((aligned(16))) bf16 Pt[4][16 * 72];

  const int tid = threadIdx.x, lane = tid & 63, w = tid >> 6;
  const int q0 = blockIdx.x * 64;
  const int bh = blockIdx.y;
  const int b = bh >> 4, h = bh & 15;
  const int l15 = lane & 15, lg = lane >> 4, rb = lg * 4;

  const bf16* Qb = Q + (size_t)bh * 2048 * 64;
  const bf16* Kb = K + (size_t)bh * 2048 * 64;
  const bf16* Vb = VT + (size_t)bh * 64 * 2048;

  bf16x8 qf[2];
  {
    const bf16* qr = Qb + (size_t)(q0 + w * 16 + l15) * 64 + lg * 8;
    qf[0] = *(const bf16x8*)(qr);
    qf[1] = *(const bf16x8*)(qr + 32);
  }

  f32x4 o[4] = {};
  float mi[4] = {-1e30f, -1e30f, -1e30f, -1e30f};
  float li[4] = {};

  for (int kv0 = 0; kv0 < 2048; kv0 += 64) {
    // stage K tile [kv][d], VT tile [d][kv] (bf16), mask tile [q][kv] (fp32->bf16)
#pragma unroll
    for (int r = 0; r < 2; ++r) {
      const int c = tid + 256 * r;
      const int row = c >> 3, c8 = (c & 7) * 8;
      *(int4v*)(Kt + row * 72 + c8) = *(const int4v*)(Kb + (size_t)(kv0 + row) * 64 + c8);
      *(int4v*)(Vt + row * 72 + c8) = *(const int4v*)(Vb + (size_t)row * 2048 + kv0 + c8);
      const float* mp = M + (size_t)(q0 + row) * 2048 + kv0 + c8;
      *(bf16x4*)(Mt + row * 72 + c8)     = cvt4(*(const f32x4*)(mp));
      *(bf16x4*)(Mt + row * 72 + c8 + 4) = cvt4(*(const f32x4*)(mp + 4));
    }
    __syncthreads();

    // S = Q K^T  (4 col-tiles of 16 kv)
    f32x4 s[4];
#pragma unroll
    for (int ct = 0; ct < 4; ++ct) {
      s[ct] = (f32x4){0.f, 0.f, 0.f, 0.f};
      const bf16* kr = Kt + (ct * 16 + l15) * 72 + lg * 8;
      s[ct] = MFMA16(qf[0], *(const bf16x8*)kr, s[ct]);
      s[ct] = MFMA16(qf[1], *(const bf16x8*)(kr + 32), s[ct]);
    }

    // scale + mask, online softmax. lane's rows: q_local = w*16 + rb + i
    float sv[4][4], tm[4];
#pragma unroll
    for (int i = 0; i < 4; ++i) {
      float t = -1e30f;
#pragma unroll
      for (int ct = 0; ct < 4; ++ct) {
        const float x = s[ct][i] * SCALE +
                        (float)Mt[(w * 16 + rb + i) * 72 + ct * 16 + l15];
        sv[ct][i] = x;
        t = fmaxf(t, x);
      }
      tm[i] = t;
    }
#pragma unroll
    for (int off = 1; off < 16; off <<= 1)
#pragma unroll
      for (int i = 0; i < 4; ++i) tm[i] = fmaxf(tm[i], __shfl_xor(tm[i], off));

    float al[4], rs[4];
#pragma unroll
    for (int i = 0; i < 4; ++i) {
      const float mn = fmaxf(mi[i], tm[i]);
      al[i] = __expf(mi[i] - mn);
      mi[i] = mn;
      rs[i] = 0.f;
    }
#pragma unroll
    for (int ct = 0; ct < 4; ++ct)
#pragma unroll
      for (int i = 0; i < 4; ++i) {
        const float p = __expf(sv[ct][i] - mi[i]);
        sv[ct][i] = p;
        rs[i] += p;
      }
#pragma unroll
    for (int off = 1; off < 16; off <<= 1)
#pragma unroll
      for (int i = 0; i < 4; ++i) rs[i] += __shfl_xor(rs[i], off);
#pragma unroll
    for (int i = 0; i < 4; ++i) li[i] = li[i] * al[i] + rs[i];
#pragma unroll
    for (int ct = 0; ct < 4; ++ct)
#pragma unroll
      for (int i = 0; i < 4; ++i) o[ct][i] *= al[i];

    // P -> per-wave LDS (D-layout), reread as A-fragments
    bf16* pw = Pt[w];
#pragma unroll
    for (int ct = 0; ct < 4; ++ct)
#pragma unroll
      for (int i = 0; i < 4; ++i)
        pw[(rb + i) * 72 + ct * 16 + l15] = (bf16)sv[ct][i];
    asm volatile("s_waitcnt lgkmcnt(0)" ::: "memory");
    __builtin_amdgcn_sched_barrier(0);

    bf16x8 pa[2];
    pa[0] = *(const bf16x8*)(pw + l15 * 72 + lg * 8);
    pa[1] = *(const bf16x8*)(pw + l15 * 72 + 32 + lg * 8);
#pragma unroll
    for (int ct = 0; ct < 4; ++ct) {
      const bf16* vr = Vt + (ct * 16 + l15) * 72 + lg * 8;
      o[ct] = MFMA16(pa[0], *(const bf16x8*)vr, o[ct]);
      o[ct] = MFMA16(pa[1], *(const bf16x8*)(vr + 32), o[ct]);
    }
    __syncthreads();
  }

  float inv[4];
#pragma unroll
  for (int i = 0; i < 4; ++i) inv[i] = 1.f / li[i];
#pragma unroll
  for (int ct = 0; ct < 4; ++ct)
#pragma unroll
    for (int i = 0; i < 4; ++i) {
      const int n = q0 + w * 16 + rb + i;
      O[((size_t)b * 2048 + n) * 1024 + h * 64 + ct * 16 + l15] =
          (bf16)(o[ct][i] * inv[i]);
    }
}

// ---------------------------------------------------------------------------
extern "C" void kernel_launch(void* const* d_in, const int* in_sizes, int n_in,
                              void* d_out, int out_size, void* d_ws, size_t ws_size,
                              hipStream_t stream)
{
  (void)in_sizes; (void)n_in; (void)out_size;
  const float* x     = (const float*)d_in[0];
  const float* fcos  = (const float*)d_in[1];
  const float* fsin  = (const float*)d_in[2];
  const float* mask  = (const float*)d_in[3];
  const float* wqkv  = (const float*)d_in[4];
  const float* wproj = (const float*)d_in[5];
  const float* bproj = (const float*)d_in[6];
  float* out = (float*)d_out;

  const size_t SZ = (size_t)64 * 2048 * 64 * 2;  // one [BH][N][64] bf16 buffer
  if (ws_size < 4 * SZ) return;                   // fail loudly (output never written)
  char* ws = (char*)d_ws;
  bf16* Qr = (bf16*)(ws);
  bf16* Kr = (bf16*)(ws + SZ);
  bf16* VT = (bf16*)(ws + 2 * SZ);
  bf16* Ob = (bf16*)(ws + 3 * SZ);

  gemm_bt<0><<<dim3(64, 24), 256, 0, stream>>>(x, wqkv, Qr, Kr, VT, nullptr);
  rope_k<<<2048, 256, 0, stream>>>(Qr, Kr, fcos, fsin);
  attn_k<<<dim3(32, 64), 256, 0, stream>>>(Qr, Kr, VT, mask, Ob);
  gemm_bt<1><<<dim3(64, 8), 256, 0, stream>>>(Ob, wproj, out, nullptr, nullptr, bproj);
}

// Round 3
// 327.552 us; speedup vs baseline: 1.2592x; 1.2592x over previous
//
#include <hip/hip_runtime.h>
#include <hip/hip_bf16.h>
#include <stdint.h>

// Problem: B=4, N=2048, C=1024, H=16, D=64.
// Device dtypes: ALL inputs fp32, output fp32. Internal: bf16 MFMA, fp32 accum.
// x @ Wqkv.T -> RoPE(q,k) -> per-(b,h) softmax(q k^T /8 + mask) v -> @ Wproj.T + b

typedef __bf16 bf16;
typedef __bf16 bf16x4 __attribute__((ext_vector_type(4)));
typedef __bf16 bf16x8 __attribute__((ext_vector_type(8)));
typedef float  f32x4  __attribute__((ext_vector_type(4)));
typedef int    int4v  __attribute__((ext_vector_type(4)));

#define MFMA16(a, b, c) __builtin_amdgcn_mfma_f32_16x16x32_bf16((a), (b), (c), 0, 0, 0)

__device__ __forceinline__ bf16x4 cvt4(f32x4 v) {
  bf16x4 r;
  r[0] = (bf16)v[0]; r[1] = (bf16)v[1]; r[2] = (bf16)v[2]; r[3] = (bf16)v[3];
  return r;
}

// ---------------------------------------------------------------------------
// GEMM: C[m][n] = sum_k A[m][k] * B[n][k]   (both K-contiguous, bf16 MFMA)
// MODE 0: A = x (fp32), B = Wqkv (fp32). Scatter: Q,K -> [BH][N][64] bf16,
//         V -> VT [BH][64][N] bf16 (transposed for attention PV).
// MODE 1: A = Ob (bf16), B = Wproj (fp32), + bias -> out fp32 [8192][1024].
// ---------------------------------------------------------------------------
template<int MODE>
__global__ __launch_bounds__(256)
void gemm_bt(const void* __restrict__ Av, const float* __restrict__ B,
             void* __restrict__ O0, bf16* __restrict__ O1, bf16* __restrict__ O2,
             const float* __restrict__ bias)
{
  constexpr int K = 1024;
  __shared__ __attribute__((aligned(16))) bf16 As[128 * 64];
  __shared__ __attribute__((aligned(16))) bf16 Bs[128 * 64];
  const int tid = threadIdx.x, lane = tid & 63, wid = tid >> 6;
  const int m0 = blockIdx.x * 128, n0 = blockIdx.y * 128;
  const int wm = (wid >> 1) * 64, wn = (wid & 1) * 64;
  const int l15 = lane & 15, lg = lane >> 4;

  f32x4 acc[4][4] = {};

  for (int k0 = 0; k0 < K; k0 += 64) {
#pragma unroll
    for (int it = 0; it < 8; ++it) {
      const int e = (it * 256 + tid) * 4;
      const int row = e >> 6, col = e & 63;
      *(bf16x4*)(Bs + row * 64 + col) =
          cvt4(*(const f32x4*)(B + (size_t)(n0 + row) * K + k0 + col));
    }
    if (MODE == 0) {
      const float* A = (const float*)Av;
#pragma unroll
      for (int it = 0; it < 8; ++it) {
        const int e = (it * 256 + tid) * 4;
        const int row = e >> 6, col = e & 63;
        *(bf16x4*)(As + row * 64 + col) =
            cvt4(*(const f32x4*)(A + (size_t)(m0 + row) * K + k0 + col));
      }
    } else {
      const bf16* A = (const bf16*)Av;
#pragma unroll
      for (int it = 0; it < 4; ++it) {
        const int e = (it * 256 + tid) * 8;
        const int row = e >> 6, col = e & 63;
        *(bf16x8*)(As + row * 64 + col) =
            *(const bf16x8*)(A + (size_t)(m0 + row) * K + k0 + col);
      }
    }
    __syncthreads();

    bf16x8 af[4][2], bb[4][2];
#pragma unroll
    for (int i = 0; i < 4; ++i)
#pragma unroll
      for (int kk = 0; kk < 2; ++kk) {
        af[i][kk] = *(const bf16x8*)(As + (wm + i * 16 + l15) * 64 + kk * 32 + lg * 8);
        bb[i][kk] = *(const bf16x8*)(Bs + (wn + i * 16 + l15) * 64 + kk * 32 + lg * 8);
      }
#pragma unroll
    for (int mi = 0; mi < 4; ++mi)
#pragma unroll
      for (int ni = 0; ni < 4; ++ni)
#pragma unroll
        for (int kk = 0; kk < 2; ++kk)
          acc[mi][ni] = MFMA16(af[mi][kk], bb[ni][kk], acc[mi][ni]);
    __syncthreads();
  }

  // epilogue. C/D layout (m89/m91): col = lane&15, row = 4*(lane>>4)+r
#pragma unroll
  for (int mi = 0; mi < 4; ++mi)
#pragma unroll
    for (int ni = 0; ni < 4; ++ni)
#pragma unroll
      for (int r = 0; r < 4; ++r) {
        const int row = m0 + wm + mi * 16 + lg * 4 + r;
        const int col = n0 + wn + ni * 16 + l15;
        float v = acc[mi][ni][r];
        if (MODE == 0) {
          const int s = col >> 10, h = (col >> 6) & 15, d = col & 63;
          const int b = row >> 11, n = row & 2047;
          const bf16 bv = (bf16)v;
          if (s == 0)
            ((bf16*)O0)[(((size_t)(b * 16 + h) * 2048) + n) * 64 + d] = bv;
          else if (s == 1)
            O1[(((size_t)(b * 16 + h) * 2048) + n) * 64 + d] = bv;
          else  // V, stored transposed: VT[bh][d][n]
            O2[(((size_t)(b * 16 + h) * 64) + d) * 2048 + n] = bv;
        } else {
          ((float*)O0)[(size_t)row * 1024 + col] = v + bias[col];
        }
      }
}

// ---------------------------------------------------------------------------
// RoPE in place on Q and K ([BH][N][64] bf16). cos/sin fp32 [B][N][32].
// ---------------------------------------------------------------------------
__global__ __launch_bounds__(256)
void rope_k(bf16* __restrict__ Q, bf16* __restrict__ K,
            const float* __restrict__ C, const float* __restrict__ S)
{
  const int gid = blockIdx.x * 256 + threadIdx.x;
  const int part = gid & 3;
  const int rowid = gid >> 2;
  const int n = rowid & 2047;
  const int b = rowid >> 15;
  const size_t cbase = ((size_t)(b * 2048 + n)) * 32 + part * 8;

  float cf[8], sf[8];
  *(f32x4*)cf = *(const f32x4*)(C + cbase);
  *(f32x4*)(cf + 4) = *(const f32x4*)(C + cbase + 4);
  *(f32x4*)sf = *(const f32x4*)(S + cbase);
  *(f32x4*)(sf + 4) = *(const f32x4*)(S + cbase + 4);

  bf16* qp = Q + (size_t)rowid * 64 + part * 16;
  bf16* kp = K + (size_t)rowid * 64 + part * 16;
  __attribute__((aligned(16))) bf16 buf[16];

  *(int4v*)buf = *(const int4v*)qp;
  *(int4v*)(buf + 8) = *(const int4v*)(qp + 8);
#pragma unroll
  for (int j = 0; j < 8; ++j) {
    const float t0 = (float)buf[2 * j], t1 = (float)buf[2 * j + 1];
    buf[2 * j]     = (bf16)(t0 * cf[j] - t1 * sf[j]);
    buf[2 * j + 1] = (bf16)(t0 * sf[j] + t1 * cf[j]);
  }
  *(int4v*)qp = *(int4v*)buf;
  *(int4v*)(qp + 8) = *(int4v*)(buf + 8);

  *(int4v*)buf = *(const int4v*)kp;
  *(int4v*)(buf + 8) = *(const int4v*)(kp + 8);
#pragma unroll
  for (int j = 0; j < 8; ++j) {
    const float t0 = (float)buf[2 * j], t1 = (float)buf[2 * j + 1];
    buf[2 * j]     = (bf16)(t0 * cf[j] - t1 * sf[j]);
    buf[2 * j + 1] = (bf16)(t0 * sf[j] + t1 * cf[j]);
  }
  *(int4v*)kp = *(int4v*)buf;
  *(int4v*)(kp + 8) = *(int4v*)(buf + 8);
}

// ---------------------------------------------------------------------------
// Flash attention, SWAPPED-QK^T softmax. 4 waves x 16 q-rows, KVBLK=64.
// QK^T computed as mfma(K, Q) -> S[kv][q]: lane (lg,l15) holds, for q-row l15,
// kv = 16*ct + 4*lg + i. Row stats are 15 in-reg ops + 2 shfl_xor.
// Mask read direct global->reg (fp32, no LDS). P scatter = 4x ds_write_b64.
// ---------------------------------------------------------------------------
__global__ __launch_bounds__(256)
void attn_k(const bf16* __restrict__ Q, const bf16* __restrict__ K,
            const bf16* __restrict__ VT, const float* __restrict__ M,
            bf16* __restrict__ O)
{
  constexpr float SCALE = 0.125f;
  __shared__ __attribute__((aligned(16))) bf16 Kt[64 * 72];
  __shared__ __attribute__((aligned(16))) bf16 Vt[64 * 72];
  __shared__ __attribute__((aligned(16))) bf16 Pt[4][16 * 72];

  const int tid = threadIdx.x, lane = tid & 63, w = tid >> 6;
  const int q0 = blockIdx.x * 64;
  const int bh = blockIdx.y;
  const int b = bh >> 4, h = bh & 15;
  const int l15 = lane & 15, lg = lane >> 4;

  const bf16* Qb = Q + (size_t)bh * 2048 * 64;
  const bf16* Kb = K + (size_t)bh * 2048 * 64;
  const bf16* Vb = VT + (size_t)bh * 64 * 2048;
  const float* Mrow = M + (size_t)(q0 + w * 16 + l15) * 2048;

  bf16x8 qf[2];
  {
    const bf16* qr = Qb + (size_t)(q0 + w * 16 + l15) * 64 + lg * 8;
    qf[0] = *(const bf16x8*)(qr);
    qf[1] = *(const bf16x8*)(qr + 32);
  }

  f32x4 o[4] = {};
  float mi_s = -1e30f, li_s = 0.f;
  bf16* pw = Pt[w];

  for (int kv0 = 0; kv0 < 2048; kv0 += 64) {
    // stage K tile [kv][d] and VT tile [d][kv] (pad 72)
#pragma unroll
    for (int r = 0; r < 2; ++r) {
      const int c = tid + 256 * r;
      const int row = c >> 3, c8 = (c & 7) * 8;
      *(int4v*)(Kt + row * 72 + c8) = *(const int4v*)(Kb + (size_t)(kv0 + row) * 64 + c8);
      *(int4v*)(Vt + row * 72 + c8) = *(const int4v*)(Vb + (size_t)row * 2048 + kv0 + c8);
    }
    // mask direct to registers (fp32); issued before barrier, used after MFMA
    f32x4 mk[4];
#pragma unroll
    for (int ct = 0; ct < 4; ++ct)
      mk[ct] = *(const f32x4*)(Mrow + kv0 + ct * 16 + lg * 4);
    __syncthreads();

    // S^T = K Q^T : s[ct][i] = S[kv = kv0+16ct+4lg+i][q = l15]
    f32x4 s[4];
#pragma unroll
    for (int ct = 0; ct < 4; ++ct) {
      s[ct] = (f32x4){0.f, 0.f, 0.f, 0.f};
      const bf16* kr = Kt + (ct * 16 + l15) * 72 + lg * 8;
      s[ct] = MFMA16(*(const bf16x8*)kr, qf[0], s[ct]);
      s[ct] = MFMA16(*(const bf16x8*)(kr + 32), qf[1], s[ct]);
    }

    // scale + fp32 mask; row max over lane-local 16 then 2 shuffles
    float tmax = -1e30f;
#pragma unroll
    for (int ct = 0; ct < 4; ++ct)
#pragma unroll
      for (int i = 0; i < 4; ++i) {
        const float x = s[ct][i] * SCALE + mk[ct][i];
        s[ct][i] = x;
        tmax = fmaxf(tmax, x);
      }
    tmax = fmaxf(tmax, __shfl_xor(tmax, 16));
    tmax = fmaxf(tmax, __shfl_xor(tmax, 32));

    const float mn = fmaxf(mi_s, tmax);
    const float al = __expf(mi_s - mn);
    mi_s = mn;

    float rs = 0.f;
#pragma unroll
    for (int ct = 0; ct < 4; ++ct)
#pragma unroll
      for (int i = 0; i < 4; ++i) {
        const float p = __expf(s[ct][i] - mn);
        s[ct][i] = p;
        rs += p;
      }
    rs += __shfl_xor(rs, 16);
    rs += __shfl_xor(rs, 32);
    li_s = li_s * al + rs;

    // o-rescale: o rows live at q = 4*lg + i; stats live at q = l15
#pragma unroll
    for (int i = 0; i < 4; ++i) {
      const float ali = __shfl(al, 4 * lg + i);
#pragma unroll
      for (int ct = 0; ct < 4; ++ct) o[ct][i] *= ali;
    }

    // P -> per-wave LDS: row q=l15, cols 16ct+4lg..+3 (aligned b64 writes)
#pragma unroll
    for (int ct = 0; ct < 4; ++ct)
      *(bf16x4*)(pw + l15 * 72 + ct * 16 + lg * 4) = cvt4(s[ct]);
    asm volatile("s_waitcnt lgkmcnt(0)" ::: "memory");
    __builtin_amdgcn_sched_barrier(0);

    bf16x8 pa[2];
    pa[0] = *(const bf16x8*)(pw + l15 * 72 + lg * 8);
    pa[1] = *(const bf16x8*)(pw + l15 * 72 + 32 + lg * 8);
#pragma unroll
    for (int ct = 0; ct < 4; ++ct) {
      const bf16* vr = Vt + (ct * 16 + l15) * 72 + lg * 8;
      o[ct] = MFMA16(pa[0], *(const bf16x8*)vr, o[ct]);
      o[ct] = MFMA16(pa[1], *(const bf16x8*)(vr + 32), o[ct]);
    }
    __syncthreads();
  }

#pragma unroll
  for (int i = 0; i < 4; ++i) {
    const float inv = 1.f / __shfl(li_s, 4 * lg + i);
    const int n = q0 + w * 16 + 4 * lg + i;
#pragma unroll
    for (int ct = 0; ct < 4; ++ct)
      O[((size_t)b * 2048 + n) * 1024 + h * 64 + ct * 16 + l15] =
          (bf16)(o[ct][i] * inv);
  }
}

// ---------------------------------------------------------------------------
extern "C" void kernel_launch(void* const* d_in, const int* in_sizes, int n_in,
                              void* d_out, int out_size, void* d_ws, size_t ws_size,
                              hipStream_t stream)
{
  (void)in_sizes; (void)n_in; (void)out_size;
  const float* x     = (const float*)d_in[0];
  const float* fcos  = (const float*)d_in[1];
  const float* fsin  = (const float*)d_in[2];
  const float* mask  = (const float*)d_in[3];
  const float* wqkv  = (const float*)d_in[4];
  const float* wproj = (const float*)d_in[5];
  const float* bproj = (const float*)d_in[6];
  float* out = (float*)d_out;

  const size_t SZ = (size_t)64 * 2048 * 64 * 2;  // one [BH][N][64] bf16 buffer
  if (ws_size < 4 * SZ) return;                   // fail loudly (output never written)
  char* ws = (char*)d_ws;
  bf16* Qr = (bf16*)(ws);
  bf16* Kr = (bf16*)(ws + SZ);
  bf16* VT = (bf16*)(ws + 2 * SZ);
  bf16* Ob = (bf16*)(ws + 3 * SZ);

  gemm_bt<0><<<dim3(64, 24), 256, 0, stream>>>(x, wqkv, Qr, Kr, VT, nullptr);
  rope_k<<<2048, 256, 0, stream>>>(Qr, Kr, fcos, fsin);
  attn_k<<<dim3(32, 64), 256, 0, stream>>>(Qr, Kr, VT, mask, Ob);
  gemm_bt<1><<<dim3(64, 8), 256, 0, stream>>>(Ob, wproj, out, nullptr, nullptr, bproj);
}